// Round 19
// baseline (225.373 us; speedup 1.0000x reference)
//
#include <hip/hip_runtime.h>

#define B 4
#define S 96
#define NN 2000
#define FF 16
#define HH 64
#define EE 16000
#define SN (S*NN)          // 192000
#define SLICES (B*S)       // 384
#define BSN (B*SN)         // 768000
#define KB_TOTAL (BSN/16)  // 48000
#define KB_PER_B (SN/16)   // 12000
#define OUT_PRED (B*24*NN*3) // 576000

typedef __attribute__((ext_vector_type(8))) short short8;
typedef __attribute__((ext_vector_type(4))) float f32x4;

__device__ __forceinline__ unsigned short f2bf(float f){
  unsigned u = __float_as_uint(f);
  u += 0x7fffu + ((u >> 16) & 1u);      // RTNE
  return (unsigned short)(u >> 16);
}
__device__ __forceinline__ float bf2f(unsigned short s){
  return __uint_as_float(((unsigned)s) << 16);
}
// tanh via v_exp_f32 + hw rcp (no IEEE divide): tanh(x) = 1 - 2/(2^(x*2*log2e)+1)
__device__ __forceinline__ float fast_tanh(float x){
  float e = __builtin_amdgcn_exp2f(x * 2.8853900817779268f);
  return 1.0f - 2.0f * __builtin_amdgcn_rcpf(e + 1.0f);
}
__device__ __forceinline__ float sigm(float x){ return 1.0f / (1.0f + __expf(-x)); }
__device__ __forceinline__ float eluf(float x){ return x > 0.0f ? x : expm1f(x); }
__device__ __forceinline__ float softplusf_(float x){
  return fmaxf(x, 0.0f) + log1pf(__expf(-fabsf(x)));
}

// ---------------- parallel CSR prep ----------------
__global__ void k_pinit(float* __restrict__ degw, int* __restrict__ cnt){
  int i = blockIdx.x * 256 + threadIdx.x;
  if (i < NN){ degw[i] = 1.0f; cnt[i] = 1; }   // self-loop preinit
}

__global__ void k_deg(const int* __restrict__ ei, const float* __restrict__ ew,
                      float* __restrict__ degw, int* __restrict__ cnt){
  int e = blockIdx.x * 256 + threadIdx.x;
  if (e < EE){
    int d = ei[EE + e];
    atomicAdd(&degw[d], ew[e]);
    atomicAdd(&cnt[d], 1);
  }
}

__global__ void k_scan(const int* __restrict__ cnt, float* __restrict__ degw,
                       int* __restrict__ rowptr, int* __restrict__ curs){
  __shared__ int tsum[256];
  int tid = threadIdx.x;
  for (int i = tid; i < NN; i += 256){
    float deg = degw[i];
    degw[i] = deg > 0.0f ? rsqrtf(deg) : 0.0f;   // becomes dinv
  }
  int base = tid * 8;
  int loc[8]; int s = 0;
  #pragma unroll
  for (int j = 0; j < 8; ++j){
    int v = (base + j < NN) ? cnt[base + j] : 0;
    loc[j] = s; s += v;
  }
  tsum[tid] = s;
  __syncthreads();
  for (int off = 1; off < 256; off <<= 1){
    int v = (tid >= off) ? tsum[tid - off] : 0;
    __syncthreads();
    tsum[tid] += v;
    __syncthreads();
  }
  int excl = tsum[tid] - s;
  #pragma unroll
  for (int j = 0; j < 8; ++j)
    if (base + j < NN){ rowptr[base + j] = excl + loc[j]; curs[base + j] = excl + loc[j]; }
  if (tid == 0) rowptr[NN] = EE + NN;
}

__global__ void k_fill(const int* __restrict__ ei, const float* __restrict__ ew,
                       const float* __restrict__ dinv, int* __restrict__ curs,
                       uint2* __restrict__ epack){
  int e = blockIdx.x * 256 + threadIdx.x;
  if (e < EE){
    int s0 = ei[e], d = ei[EE + e];
    int pos = atomicAdd(&curs[d], 1);
    epack[pos] = make_uint2((unsigned)s0, __float_as_uint(dinv[s0] * ew[e] * dinv[d]));
  }
  int i = blockIdx.x * 256 + threadIdx.x;
  if (i < NN){
    int pos = atomicAdd(&curs[i], 1);
    epack[pos] = make_uint2((unsigned)i, __float_as_uint(dinv[i] * dinv[i]));
  }
}

// ------------- GCN aggregate: block = (slice-pair, featHalf); 1 edge-walk covers 2 slices -------------
__global__ __launch_bounds__(512) void k_agg(const float* __restrict__ x,
    const int* __restrict__ rowptr, const uint2* __restrict__ epack,
    unsigned* __restrict__ aggG){
  __shared__ unsigned xs[2][NN * 4];   // 64000 B (2 slices x half-features, bf16)
  int tid = threadIdx.x;
  int spair = blockIdx.x >> 1;
  int halfF = blockIdx.x & 1;          // features [halfF*8, halfF*8+8)
  int s0 = spair * 2;

  #pragma unroll
  for (int ss = 0; ss < 2; ++ss){
    const float* xg = x + (size_t)(s0 + ss) * (NN * FF) + halfF * 8;
    for (int i = tid; i < 4000; i += 512){
      int n = i >> 1, p = i & 1;
      float4 v = *(const float4*)(xg + n * 16 + p * 4);
      xs[ss][n * 4 + p * 2]     = (unsigned)f2bf(v.x) | ((unsigned)f2bf(v.y) << 16);
      xs[ss][n * 4 + p * 2 + 1] = (unsigned)f2bf(v.z) | ((unsigned)f2bf(v.w) << 16);
    }
  }
  __syncthreads();

  int rs[4], re[4];
  #pragma unroll
  for (int g = 0; g < 4; ++g){
    int n = g * 512 + tid;
    if (n < NN){ rs[g] = rowptr[n]; re[g] = rowptr[n + 1]; }
    else { rs[g] = 0; re[g] = 0; }
  }
  float agg[4][2][8];
  #pragma unroll
  for (int g = 0; g < 4; ++g)
    #pragma unroll
    for (int ss = 0; ss < 2; ++ss)
      #pragma unroll
      for (int i = 0; i < 8; ++i) agg[g][ss][i] = 0.0f;

  #pragma unroll
  for (int g = 0; g < 4; ++g){
    for (int e = rs[g]; e < re[g]; ++e){
      uint2 m = epack[e];
      int s = (int)m.x;
      float c = __uint_as_float(m.y);
      uint4 u0 = *(const uint4*)&xs[0][s * 4];
      uint4 u1 = *(const uint4*)&xs[1][s * 4];
      agg[g][0][0] += c * __uint_as_float(u0.x << 16);
      agg[g][0][1] += c * __uint_as_float(u0.x & 0xffff0000u);
      agg[g][0][2] += c * __uint_as_float(u0.y << 16);
      agg[g][0][3] += c * __uint_as_float(u0.y & 0xffff0000u);
      agg[g][0][4] += c * __uint_as_float(u0.z << 16);
      agg[g][0][5] += c * __uint_as_float(u0.z & 0xffff0000u);
      agg[g][0][6] += c * __uint_as_float(u0.w << 16);
      agg[g][0][7] += c * __uint_as_float(u0.w & 0xffff0000u);
      agg[g][1][0] += c * __uint_as_float(u1.x << 16);
      agg[g][1][1] += c * __uint_as_float(u1.x & 0xffff0000u);
      agg[g][1][2] += c * __uint_as_float(u1.y << 16);
      agg[g][1][3] += c * __uint_as_float(u1.y & 0xffff0000u);
      agg[g][1][4] += c * __uint_as_float(u1.z << 16);
      agg[g][1][5] += c * __uint_as_float(u1.z & 0xffff0000u);
      agg[g][1][6] += c * __uint_as_float(u1.w << 16);
      agg[g][1][7] += c * __uint_as_float(u1.w & 0xffff0000u);
    }
  }
  #pragma unroll
  for (int g = 0; g < 4; ++g){
    int n = g * 512 + tid;
    if (n < NN){
      #pragma unroll
      for (int ss = 0; ss < 2; ++ss){
        unsigned u[4];
        #pragma unroll
        for (int j = 0; j < 4; ++j)
          u[j] = (unsigned)f2bf(agg[g][ss][2*j]) | ((unsigned)f2bf(agg[g][ss][2*j+1]) << 16);
        uint4* dst = (uint4*)(aggG + ((size_t)(s0 + ss) * NN + n) * 8 + halfF * 4);
        *dst = make_uint4(u[0], u[1], u[2], u[3]);
      }
    }
  }
}

// ------------- transform: h = elu(agg @ Wg^T + b) via MFMA, 16 nodes/wave-iter -------------
__global__ __launch_bounds__(256) void k_xform(const unsigned short* __restrict__ aggG,
    const float* __restrict__ Wg, const float* __restrict__ bg,
    unsigned short* __restrict__ h){
  int lane = threadIdx.x & 63;
  int wid  = threadIdx.x >> 6;
  int wgid = blockIdx.x * 4 + wid;          // 0..8191
  int row16 = lane & 15, half = lane >> 4;

  short8 bf[4];
  #pragma unroll
  for (int t = 0; t < 4; ++t){
    short8 v;
    #pragma unroll
    for (int j = 0; j < 8; ++j) v[j] = 0;
    if (half < 2){
      const float* wr = Wg + (t * 16 + row16) * 16 + half * 8;
      #pragma unroll
      for (int j = 0; j < 8; ++j) v[j] = (short)f2bf(wr[j]);
    }
    bf[t] = v;
  }
  float bias[4];
  #pragma unroll
  for (int t = 0; t < 4; ++t) bias[t] = bg[t * 16 + row16];

  for (int nb = wgid; nb < KB_TOTAL; nb += 8192){
    short8 af;
    #pragma unroll
    for (int j = 0; j < 8; ++j) af[j] = 0;
    if (half < 2)
      af = *(const short8*)(aggG + ((size_t)nb * 16 + row16) * 16 + half * 8);

    f32x4 acc[4];
    #pragma unroll
    for (int t = 0; t < 4; ++t){
      f32x4 a = {0.f, 0.f, 0.f, 0.f};
      acc[t] = __builtin_amdgcn_mfma_f32_16x16x32_bf16(af, bf[t], a, 0, 0, 0);
    }
    unsigned short* hp = h + (size_t)nb * 16 * 64;
    #pragma unroll
    for (int t = 0; t < 4; ++t){
      #pragma unroll
      for (int r = 0; r < 4; ++r){
        float v = acc[t][r] + bias[t];
        float e = v > 0.0f ? v : __expf(v) - 1.0f;
        hp[(half * 4 + r) * 64 + t * 16 + row16] = f2bf(e);
      }
    }
  }
}

// ------------- query = mean over nodes at s=S-1; qp = query @ Wq^T -------------
__global__ void k_query(const unsigned short* __restrict__ h,
                        const float* __restrict__ Wq, float* __restrict__ qp){
  __shared__ float part[256];
  __shared__ float q[64];
  int b = blockIdx.x, tid = threadIdx.x;
  int i = tid & 63, chunk = tid >> 6;
  const unsigned short* hb = h + ((size_t)(b * S + (S - 1)) * NN) * HH;
  float p = 0.0f;
  for (int n = chunk * 500; n < chunk * 500 + 500; ++n) p += bf2f(hb[n * HH + i]);
  part[tid] = p;
  __syncthreads();
  if (tid < 64) q[tid] = (part[tid] + part[tid+64] + part[tid+128] + part[tid+192]) * (1.0f / NN);
  __syncthreads();
  if (tid < 64){
    float acc = 0.0f;
    for (int k = 0; k < 64; ++k) acc += q[k] * Wq[tid * 64 + k];
    qp[b * 64 + tid] = acc;
  }
}

// ------------- scores: kp = keys @ Wk^T via MFMA; score = v . tanh(qp + kp) -------------
// wave owns 6 CONTIGUOUS key-blocks (never crosses a batch: 12000 = 6*2000)
__global__ __launch_bounds__(256) void k_scores(const unsigned short* __restrict__ h,
    const float* __restrict__ Wk, const float* __restrict__ vw,
    const float* __restrict__ qp, float* __restrict__ scores){
  int lane = threadIdx.x & 63;
  int wid = threadIdx.x >> 6;
  int wgid = blockIdx.x * 4 + wid;          // 0..7999
  int row16 = lane & 15, half = lane >> 4;

  short8 bf[4][2];
  #pragma unroll
  for (int t = 0; t < 4; ++t){
    int n = 16 * t + row16;
    #pragma unroll
    for (int s2 = 0; s2 < 2; ++s2){
      const float* wr = Wk + n * 64 + 32 * s2 + half * 8;
      short8 v;
      #pragma unroll
      for (int j = 0; j < 8; ++j) v[j] = (short)f2bf(wr[j]);
      bf[t][s2] = v;
    }
  }
  float vwv[4];
  #pragma unroll
  for (int t = 0; t < 4; ++t) vwv[t] = vw[16 * t + row16];

  int b = wgid / 2000;                       // batch is loop-invariant
  float qv[4];
  #pragma unroll
  for (int t = 0; t < 4; ++t) qv[t] = qp[b * 64 + 16 * t + row16];

  int kb0 = wgid * 6;
  #pragma unroll 2
  for (int i = 0; i < 6; ++i){
    int kb = kb0 + i;
    const short* hp = (const short*)h + (size_t)kb * 16 * 64;
    short8 af[2];
    #pragma unroll
    for (int s2 = 0; s2 < 2; ++s2)
      af[s2] = *(const short8*)(hp + row16 * 64 + 32 * s2 + half * 8);

    f32x4 acc[4];
    #pragma unroll
    for (int t = 0; t < 4; ++t){
      f32x4 a = {0.f, 0.f, 0.f, 0.f};
      a = __builtin_amdgcn_mfma_f32_16x16x32_bf16(af[0], bf[t][0], a, 0, 0, 0);
      a = __builtin_amdgcn_mfma_f32_16x16x32_bf16(af[1], bf[t][1], a, 0, 0, 0);
      acc[t] = a;
    }
    float part[4] = {0, 0, 0, 0};
    #pragma unroll
    for (int t = 0; t < 4; ++t){
      #pragma unroll
      for (int r = 0; r < 4; ++r)
        part[r] += vwv[t] * fast_tanh(qv[t] + acc[t][r]);
    }
    #pragma unroll
    for (int r = 0; r < 4; ++r){
      part[r] += __shfl_xor(part[r], 1);
      part[r] += __shfl_xor(part[r], 2);
      part[r] += __shfl_xor(part[r], 4);
      part[r] += __shfl_xor(part[r], 8);
    }
    if (row16 == 0){
      #pragma unroll
      for (int r = 0; r < 4; ++r) scores[kb * 16 + half * 4 + r] = part[r];
    }
  }
}

// ------------- softmax reductions over SN per batch -------------
__global__ void k_smax1(const float* __restrict__ scores, float* __restrict__ part2){
  __shared__ float red[256];
  int b = blockIdx.x >> 7, blk = blockIdx.x & 127, tid = threadIdx.x;
  const float* sc = scores + (size_t)b * SN + blk * 1500;
  float m = -1e30f;
  for (int k = tid; k < 1500; k += 256) m = fmaxf(m, sc[k]);
  red[tid] = m; __syncthreads();
  for (int s2 = 128; s2 > 0; s2 >>= 1){
    if (tid < s2) red[tid] = fmaxf(red[tid], red[tid + s2]);
    __syncthreads();
  }
  float bm = red[0]; __syncthreads();
  float sum = 0.f;
  for (int k = tid; k < 1500; k += 256) sum += __expf(sc[k] - bm);
  red[tid] = sum; __syncthreads();
  for (int s2 = 128; s2 > 0; s2 >>= 1){
    if (tid < s2) red[tid] += red[tid + s2];
    __syncthreads();
  }
  if (tid == 0){
    part2[(b * 128 + blk) * 2]     = bm;
    part2[(b * 128 + blk) * 2 + 1] = red[0];
  }
}

__global__ void k_smax2(const float* __restrict__ part2, float* __restrict__ Msum){
  int b = threadIdx.x;
  if (b < B){
    float M = -1e30f;
    for (int i = 0; i < 128; ++i) M = fmaxf(M, part2[(b * 128 + i) * 2]);
    float Ssum = 0.f;
    for (int i = 0; i < 128; ++i)
      Ssum += part2[(b * 128 + i) * 2 + 1] * __expf(part2[(b * 128 + i) * 2] - M);
    Msum[b] = M;
    Msum[4 + b] = 1.0f / Ssum;
  }
}

// ------------- fused: attn write + ctx_raw via h recompute from aggG -------------
// wave owns 12 contiguous key-blocks; recomputes h tile with the k_xform MFMA
__global__ __launch_bounds__(256) void k_ctx(const float* __restrict__ scores,
    const float* __restrict__ Msum, const unsigned short* __restrict__ aggG,
    const float* __restrict__ Wg, const float* __restrict__ bg,
    float* __restrict__ ctx_raw, float* __restrict__ outp){
  __shared__ float red[4 * 64];
  int lane = threadIdx.x & 63, wid = threadIdx.x >> 6;
  int wgid = blockIdx.x * 4 + wid;           // 0..3999
  int row16 = lane & 15, half = lane >> 4;

  short8 bf[4];
  #pragma unroll
  for (int t = 0; t < 4; ++t){
    short8 v;
    #pragma unroll
    for (int j = 0; j < 8; ++j) v[j] = 0;
    if (half < 2){
      const float* wr = Wg + (t * 16 + row16) * 16 + half * 8;
      #pragma unroll
      for (int j = 0; j < 8; ++j) v[j] = (short)f2bf(wr[j]);
    }
    bf[t] = v;
  }
  float bias[4];
  #pragma unroll
  for (int t = 0; t < 4; ++t) bias[t] = bg[t * 16 + row16];

  int b = wgid / 1000;                       // 12000 = 12*1000 -> batch-uniform
  float M = Msum[b], Si = Msum[4 + b];
  float* ao = outp + OUT_PRED;               // kb*16 is already a GLOBAL key index

  float acc4[4] = {0.f, 0.f, 0.f, 0.f};
  int kb0 = wgid * 12;
  for (int i = 0; i < 12; ++i){
    int kb = kb0 + i;
    short8 af;
    #pragma unroll
    for (int j = 0; j < 8; ++j) af[j] = 0;
    if (half < 2)
      af = *(const short8*)(aggG + ((size_t)kb * 16 + row16) * 16 + half * 8);

    f32x4 hz[4];
    #pragma unroll
    for (int t = 0; t < 4; ++t){
      f32x4 a = {0.f, 0.f, 0.f, 0.f};
      hz[t] = __builtin_amdgcn_mfma_f32_16x16x32_bf16(af, bf[t], a, 0, 0, 0);
    }
    float ar[4];
    #pragma unroll
    for (int r = 0; r < 4; ++r)
      ar[r] = __expf(scores[kb * 16 + half * 4 + r] - M) * Si;
    if (row16 == 0){
      #pragma unroll
      for (int r = 0; r < 4; ++r) ao[kb * 16 + half * 4 + r] = ar[r];
    }
    #pragma unroll
    for (int t = 0; t < 4; ++t){
      #pragma unroll
      for (int r = 0; r < 4; ++r){
        float v = hz[t][r] + bias[t];
        float e = v > 0.0f ? v : __expf(v) - 1.0f;
        e = __uint_as_float(((unsigned)f2bf(e)) << 16);  // match stored-h bf16 rounding
        acc4[t] += ar[r] * e;
      }
    }
  }
  #pragma unroll
  for (int t = 0; t < 4; ++t){
    acc4[t] += __shfl_xor(acc4[t], 16);
    acc4[t] += __shfl_xor(acc4[t], 32);
  }
  if (half == 0){
    #pragma unroll
    for (int t = 0; t < 4; ++t) red[wid * 64 + t * 16 + row16] = acc4[t];
  }
  __syncthreads();
  if (wid == 0){
    float tsum = red[lane] + red[64 + lane] + red[128 + lane] + red[192 + lane];
    atomicAdd(&ctx_raw[b * 64 + lane], tsum);
  }
}

// ------------- Wv, LN1, GRU x2, LN2, pre1 (tiny, 1 block/batch, 128 thr) -------------
__global__ void k_head(const float* __restrict__ ctx_raw, const float* __restrict__ Wv,
    const float* __restrict__ ln1g, const float* __restrict__ ln1b,
    const float* __restrict__ Wih, const float* __restrict__ bih,
    const float* __restrict__ bhh,
    const float* __restrict__ ln2g, const float* __restrict__ ln2b,
    const float* __restrict__ pre1W, const float* __restrict__ pre1b,
    float* __restrict__ fout){
  __shared__ float cr[64], vec[64], stat[2];
  int b = blockIdx.x, t = threadIdx.x;
  if (t < 64) cr[t] = ctx_raw[b * 64 + t];
  __syncthreads();
  float c = 0.f;
  if (t < 64){
    for (int i = 0; i < 64; ++i) c += cr[i] * Wv[t * 64 + i];
  }
  __syncthreads();
  if (t < 64) vec[t] = c;
  __syncthreads();
  if (t == 0){
    float mu = 0; for (int i = 0; i < 64; ++i) mu += vec[i]; mu *= (1.f/64.f);
    float va = 0; for (int i = 0; i < 64; ++i){ float d = vec[i] - mu; va += d * d; }
    va *= (1.f/64.f);
    stat[0] = mu; stat[1] = rsqrtf(va + 1e-5f);
  }
  __syncthreads();
  if (t < 64) cr[t] = (vec[t] - stat[0]) * stat[1] * ln1g[t] + ln1b[t];
  __syncthreads();
  for (int l = 0; l < 2; ++l){
    float nv = 0.f;
    if (t < 64){
      const float* W = Wih + l * 192 * 64;
      const float* bi = bih + l * 192;
      const float* bh = bhh + l * 192;
      float ir = bi[t], iz = bi[64 + t], in_ = bi[128 + t];
      for (int i = 0; i < 64; ++i){
        float v = cr[i];
        ir  += v * W[t * 64 + i];
        iz  += v * W[(64 + t) * 64 + i];
        in_ += v * W[(128 + t) * 64 + i];
      }
      float r = sigm(ir + bh[t]);
      float z = sigm(iz + bh[64 + t]);
      float nn2 = fast_tanh(in_ + r * bh[128 + t]);
      nv = (1.0f - z) * nn2;
    }
    __syncthreads();
    if (t < 64) cr[t] = nv;
    __syncthreads();
  }
  if (t == 0){
    float mu = 0; for (int i = 0; i < 64; ++i) mu += cr[i]; mu *= (1.f/64.f);
    float va = 0; for (int i = 0; i < 64; ++i){ float d = cr[i] - mu; va += d * d; }
    va *= (1.f/64.f);
    stat[0] = mu; stat[1] = rsqrtf(va + 1e-5f);
  }
  __syncthreads();
  if (t < 64) vec[t] = (cr[t] - stat[0]) * stat[1] * ln2g[t] + ln2b[t];
  __syncthreads();
  float fc = pre1b[t];
  for (int j = 0; j < 64; ++j) fc += vec[j] * pre1W[t * 64 + j];
  fout[b * 128 + t] = eluf(fc);
}

// ------------- pre2 projection (MFMA) + monotonic quantile head -------------
__global__ __launch_bounds__(256) void k_out(const float* __restrict__ f_g,
    const float* __restrict__ pre2W, const float* __restrict__ pre2b,
    const float* __restrict__ lowW, const float* __restrict__ lowb,
    const float* __restrict__ incW, const float* __restrict__ incb,
    float* __restrict__ outp){
  __shared__ float w72T[64 * 72];          // head weights transposed [j][out], 18.4 KB
  __shared__ float nf_lds[4][64 * 4];      // per-wave nf[j][b], 4 KB
  int tid = threadIdx.x;
  int lane = tid & 63, wid = tid >> 6;
  int row16 = lane & 15, half = lane >> 4;

  for (int i = tid; i < 64 * 72; i += 256){
    int j = i / 72, o = i - j * 72;
    w72T[i] = (o < 24) ? lowW[o * 64 + j] : incW[(o - 24) * 64 + j];
  }

  short8 bfr[4];
  #pragma unroll
  for (int s = 0; s < 4; ++s){
    short8 v;
    #pragma unroll
    for (int j = 0; j < 8; ++j) v[j] = 0;
    if (row16 < 4){
      const float* fr = f_g + row16 * 128 + s * 32 + half * 8;
      #pragma unroll
      for (int j = 0; j < 8; ++j) v[j] = (short)f2bf(fr[j]);
    }
    bfr[s] = v;
  }
  __syncthreads();

  int n = blockIdx.x * 4 + wid;            // exactly 2000 nodes
  float* nfw = &nf_lds[wid][0];
  #pragma unroll
  for (int rb = 0; rb < 4; ++rb){
    f32x4 acc = {0.f, 0.f, 0.f, 0.f};
    #pragma unroll
    for (int s = 0; s < 4; ++s){
      const float* ar = pre2W + ((size_t)(n * 64 + rb * 16 + row16)) * 128 + s * 32 + half * 8;
      short8 av;
      #pragma unroll
      for (int j = 0; j < 8; ++j) av[j] = (short)f2bf(ar[j]);
      acc = __builtin_amdgcn_mfma_f32_16x16x32_bf16(av, bfr[s], acc, 0, 0, 0);
    }
    if (row16 < 4){
      #pragma unroll
      for (int r = 0; r < 4; ++r){
        int j = rb * 16 + half * 4 + r;
        nfw[j * 4 + row16] = acc[r] + pre2b[n * 64 + j];
      }
    }
  }
  __syncthreads();

  #pragma unroll
  for (int rnd = 0; rnd < 2; ++rnd){
    int wo = rnd * 16 + (lane >> 2);
    int b = lane & 3;
    if (wo < 24){
      float q0 = lowb[wo], i0 = incb[2 * wo], i1 = incb[2 * wo + 1];
      #pragma unroll 4
      for (int j = 0; j < 64; ++j){
        float v = nfw[j * 4 + b];
        q0 += v * w72T[j * 72 + wo];
        i0 += v * w72T[j * 72 + 24 + 2 * wo];
        i1 += v * w72T[j * 72 + 24 + 2 * wo + 1];
      }
      float p0 = q0;
      float p1 = p0 + softplusf_(i0);
      float p2 = p1 + softplusf_(i1);
      size_t ob = ((size_t)(b * 24 + wo) * NN + n) * 3;
      outp[ob] = p0; outp[ob + 1] = p1; outp[ob + 2] = p2;
    }
  }
}

extern "C" void kernel_launch(void* const* d_in, const int* in_sizes, int n_in,
                              void* d_out, int out_size, void* d_ws, size_t ws_size,
                              hipStream_t stream){
  const float* x     = (const float*)d_in[0];
  const int*   ei    = (const int*)d_in[1];
  const float* ew    = (const float*)d_in[2];
  const float* Wg    = (const float*)d_in[3];
  const float* bg    = (const float*)d_in[4];
  const float* Wq    = (const float*)d_in[5];
  const float* Wk    = (const float*)d_in[6];
  const float* Wv    = (const float*)d_in[7];
  const float* vw    = (const float*)d_in[8];
  const float* ln1g  = (const float*)d_in[10];
  const float* ln1b  = (const float*)d_in[11];
  const float* Wih   = (const float*)d_in[12];
  const float* bih   = (const float*)d_in[14];
  const float* bhh   = (const float*)d_in[15];
  const float* ln2g  = (const float*)d_in[16];
  const float* ln2b  = (const float*)d_in[17];
  const float* pre1W = (const float*)d_in[18];
  const float* pre1b = (const float*)d_in[19];
  const float* pre2W = (const float*)d_in[20];
  const float* pre2b = (const float*)d_in[21];
  const float* lowW  = (const float*)d_in[22];
  const float* lowb  = (const float*)d_in[23];
  const float* incW  = (const float*)d_in[24];
  const float* incb  = (const float*)d_in[25];
  float* outp = (float*)d_out;

  char* ws = (char*)d_ws;
  size_t off = 0;
  auto alloc = [&](size_t bytes) -> char* {
    char* p = ws + off;
    off += (bytes + 255) & ~(size_t)255;
    return p;
  };
  unsigned short* h  = (unsigned short*)alloc((size_t)BSN * 64 * 2); // 98.3 MB bf16
  unsigned* aggG     = (unsigned*)alloc((size_t)BSN * 8 * 4);        // 24.6 MB bf16-packed
  float* scores      = (float*)alloc((size_t)BSN * 4);
  int*   rowptr      = (int*)alloc((NN + 1) * 4);
  uint2* epack       = (uint2*)alloc((EE + NN) * 8);
  float* degw        = (float*)alloc(NN * 4);
  int*   cnt         = (int*)alloc(NN * 4);
  int*   curs        = (int*)alloc(NN * 4);
  float* qp          = (float*)alloc(B * 64 * 4);
  float* part2       = (float*)alloc(B * 128 * 2 * 4);
  float* Msum        = (float*)alloc(8 * 4);
  float* ctx_raw     = (float*)alloc(B * 64 * 4);
  float* f_g         = (float*)alloc(B * 128 * 4);
  (void)ws_size; (void)in_sizes; (void)n_in; (void)out_size;

  (void)hipMemsetAsync(ctx_raw, 0, B * 64 * 4, stream);
  k_pinit <<<(NN + 255) / 256, 256, 0, stream>>>(degw, cnt);
  k_deg   <<<(EE + 255) / 256, 256, 0, stream>>>(ei, ew, degw, cnt);
  k_scan  <<<1, 256, 0, stream>>>(cnt, degw, rowptr, curs);
  k_fill  <<<(EE + 255) / 256, 256, 0, stream>>>(ei, ew, degw, curs, epack);
  k_agg   <<<SLICES, 512, 0, stream>>>(x, rowptr, epack, aggG);
  k_xform <<<2048, 256, 0, stream>>>((const unsigned short*)aggG, Wg, bg, h);
  k_query <<<B, 256, 0, stream>>>(h, Wq, qp);
  k_scores<<<2000, 256, 0, stream>>>(h, Wk, vw, qp, scores);
  k_smax1 <<<512, 256, 0, stream>>>(scores, part2);
  k_smax2 <<<1, 64, 0, stream>>>(part2, Msum);
  k_ctx   <<<1000, 256, 0, stream>>>(scores, Msum, (const unsigned short*)aggG, Wg, bg,
                                     ctx_raw, outp);
  k_head  <<<B, 128, 0, stream>>>(ctx_raw, Wv, ln1g, ln1b, Wih, bih, bhh,
                                  ln2g, ln2b, pre1W, pre1b, f_g);
  k_out   <<<500, 256, 0, stream>>>(f_g, pre2W, pre2b, lowW, lowb, incW, incb, outp);
}

// Round 20
// 215.667 us; speedup vs baseline: 1.0450x; 1.0450x over previous
//
#include <hip/hip_runtime.h>

#define B 4
#define S 96
#define NN 2000
#define FF 16
#define HH 64
#define EE 16000
#define SN (S*NN)          // 192000
#define SLICES (B*S)       // 384
#define BSN (B*SN)         // 768000
#define KB_TOTAL (BSN/16)  // 48000
#define KB_PER_B (SN/16)   // 12000
#define OUT_PRED (B*24*NN*3) // 576000

typedef __attribute__((ext_vector_type(8))) short short8;
typedef __attribute__((ext_vector_type(4))) float f32x4;

__device__ __forceinline__ unsigned short f2bf(float f){
  unsigned u = __float_as_uint(f);
  u += 0x7fffu + ((u >> 16) & 1u);      // RTNE
  return (unsigned short)(u >> 16);
}
__device__ __forceinline__ float bf2f(unsigned short s){
  return __uint_as_float(((unsigned)s) << 16);
}
// tanh via v_exp_f32 + hw rcp (no IEEE divide): tanh(x) = 1 - 2/(2^(x*2*log2e)+1)
__device__ __forceinline__ float fast_tanh(float x){
  float e = __builtin_amdgcn_exp2f(x * 2.8853900817779268f);
  return 1.0f - 2.0f * __builtin_amdgcn_rcpf(e + 1.0f);
}
__device__ __forceinline__ float sigm(float x){ return 1.0f / (1.0f + __expf(-x)); }
__device__ __forceinline__ float eluf(float x){ return x > 0.0f ? x : expm1f(x); }
__device__ __forceinline__ float softplusf_(float x){
  return fmaxf(x, 0.0f) + log1pf(__expf(-fabsf(x)));
}

// ---------------- parallel CSR prep ----------------
__global__ void k_pinit(float* __restrict__ degw, int* __restrict__ cnt){
  int i = blockIdx.x * 256 + threadIdx.x;
  if (i < NN){ degw[i] = 1.0f; cnt[i] = 1; }   // self-loop preinit
}

__global__ void k_deg(const int* __restrict__ ei, const float* __restrict__ ew,
                      float* __restrict__ degw, int* __restrict__ cnt){
  int e = blockIdx.x * 256 + threadIdx.x;
  if (e < EE){
    int d = ei[EE + e];
    atomicAdd(&degw[d], ew[e]);
    atomicAdd(&cnt[d], 1);
  }
}

__global__ void k_scan(const int* __restrict__ cnt, float* __restrict__ degw,
                       int* __restrict__ rowptr, int* __restrict__ curs){
  __shared__ int tsum[256];
  int tid = threadIdx.x;
  for (int i = tid; i < NN; i += 256){
    float deg = degw[i];
    degw[i] = deg > 0.0f ? rsqrtf(deg) : 0.0f;   // becomes dinv
  }
  int base = tid * 8;
  int loc[8]; int s = 0;
  #pragma unroll
  for (int j = 0; j < 8; ++j){
    int v = (base + j < NN) ? cnt[base + j] : 0;
    loc[j] = s; s += v;
  }
  tsum[tid] = s;
  __syncthreads();
  for (int off = 1; off < 256; off <<= 1){
    int v = (tid >= off) ? tsum[tid - off] : 0;
    __syncthreads();
    tsum[tid] += v;
    __syncthreads();
  }
  int excl = tsum[tid] - s;
  #pragma unroll
  for (int j = 0; j < 8; ++j)
    if (base + j < NN){ rowptr[base + j] = excl + loc[j]; curs[base + j] = excl + loc[j]; }
  if (tid == 0) rowptr[NN] = EE + NN;
}

__global__ void k_fill(const int* __restrict__ ei, const float* __restrict__ ew,
                       const float* __restrict__ dinv, int* __restrict__ curs,
                       uint2* __restrict__ epack){
  int e = blockIdx.x * 256 + threadIdx.x;
  if (e < EE){
    int s0 = ei[e], d = ei[EE + e];
    int pos = atomicAdd(&curs[d], 1);
    epack[pos] = make_uint2((unsigned)s0, __float_as_uint(dinv[s0] * ew[e] * dinv[d]));
  }
  int i = blockIdx.x * 256 + threadIdx.x;
  if (i < NN){
    int pos = atomicAdd(&curs[i], 1);
    epack[pos] = make_uint2((unsigned)i, __float_as_uint(dinv[i] * dinv[i]));
  }
}

// ------------- GCN aggregate: single-pass bf16 LDS, packed metadata -------------
__global__ __launch_bounds__(512) void k_agg(const float* __restrict__ x,
    const int* __restrict__ rowptr, const uint2* __restrict__ epack,
    unsigned* __restrict__ aggG){
  __shared__ unsigned xs[NN * 8];   // 64000 B exactly
  int tid = threadIdx.x;
  int slice = blockIdx.x;
  const float4* xg4 = (const float4*)(x + (size_t)slice * (NN * FF)); // 8000 float4
  for (int i = tid; i < 8000; i += 512){
    float4 v = xg4[i];
    int sl = i >> 2, q = i & 3;           // q = which float4 of the row
    unsigned p0 = (unsigned)f2bf(v.x) | ((unsigned)f2bf(v.y) << 16);
    unsigned p1 = (unsigned)f2bf(v.z) | ((unsigned)f2bf(v.w) << 16);
    int j  = q >> 1;                       // uint4 slot (0/1)
    int jj = (j + (sl >> 1)) & 1;          // swizzle
    int base = sl * 8 + jj * 4 + (q & 1) * 2;
    xs[base] = p0; xs[base + 1] = p1;
  }
  __syncthreads();

  int rs[4], re[4];
  #pragma unroll
  for (int g = 0; g < 4; ++g){
    int n = g * 512 + tid;
    if (n < NN){ rs[g] = rowptr[n]; re[g] = rowptr[n + 1]; }
    else { rs[g] = 0; re[g] = 0; }
  }
  float agg[4][16];
  #pragma unroll
  for (int g = 0; g < 4; ++g)
    #pragma unroll
    for (int i = 0; i < 16; ++i) agg[g][i] = 0.0f;

  #pragma unroll
  for (int g = 0; g < 4; ++g){
    for (int e = rs[g]; e < re[g]; ++e){
      uint2 m = epack[e];
      int s = (int)m.x;
      float c = __uint_as_float(m.y);
      int r0 = ((s >> 1) & 1) * 4;
      uint4 ua = *(const uint4*)&xs[s * 8 + r0];
      uint4 ub = *(const uint4*)&xs[s * 8 + (r0 ^ 4)];
      agg[g][0]  += c * __uint_as_float(ua.x << 16);
      agg[g][1]  += c * __uint_as_float(ua.x & 0xffff0000u);
      agg[g][2]  += c * __uint_as_float(ua.y << 16);
      agg[g][3]  += c * __uint_as_float(ua.y & 0xffff0000u);
      agg[g][4]  += c * __uint_as_float(ua.z << 16);
      agg[g][5]  += c * __uint_as_float(ua.z & 0xffff0000u);
      agg[g][6]  += c * __uint_as_float(ua.w << 16);
      agg[g][7]  += c * __uint_as_float(ua.w & 0xffff0000u);
      agg[g][8]  += c * __uint_as_float(ub.x << 16);
      agg[g][9]  += c * __uint_as_float(ub.x & 0xffff0000u);
      agg[g][10] += c * __uint_as_float(ub.y << 16);
      agg[g][11] += c * __uint_as_float(ub.y & 0xffff0000u);
      agg[g][12] += c * __uint_as_float(ub.z << 16);
      agg[g][13] += c * __uint_as_float(ub.z & 0xffff0000u);
      agg[g][14] += c * __uint_as_float(ub.w << 16);
      agg[g][15] += c * __uint_as_float(ub.w & 0xffff0000u);
    }
  }
  #pragma unroll
  for (int g = 0; g < 4; ++g){
    int n = g * 512 + tid;
    if (n < NN){
      unsigned u[8];
      #pragma unroll
      for (int j = 0; j < 8; ++j)
        u[j] = (unsigned)f2bf(agg[g][2*j]) | ((unsigned)f2bf(agg[g][2*j+1]) << 16);
      uint4* dst = (uint4*)(aggG + ((size_t)slice * NN + n) * 8);
      dst[0] = make_uint4(u[0], u[1], u[2], u[3]);
      dst[1] = make_uint4(u[4], u[5], u[6], u[7]);
    }
  }
}

// ------------- transform: h = elu(agg @ Wg^T + b) via MFMA, 16 nodes/wave-iter -------------
__global__ __launch_bounds__(256) void k_xform(const unsigned short* __restrict__ aggG,
    const float* __restrict__ Wg, const float* __restrict__ bg,
    unsigned short* __restrict__ h){
  int lane = threadIdx.x & 63;
  int wid  = threadIdx.x >> 6;
  int wgid = blockIdx.x * 4 + wid;          // 0..8191
  int row16 = lane & 15, half = lane >> 4;

  short8 bf[4];
  #pragma unroll
  for (int t = 0; t < 4; ++t){
    short8 v;
    #pragma unroll
    for (int j = 0; j < 8; ++j) v[j] = 0;
    if (half < 2){
      const float* wr = Wg + (t * 16 + row16) * 16 + half * 8;
      #pragma unroll
      for (int j = 0; j < 8; ++j) v[j] = (short)f2bf(wr[j]);
    }
    bf[t] = v;
  }
  float bias[4];
  #pragma unroll
  for (int t = 0; t < 4; ++t) bias[t] = bg[t * 16 + row16];

  for (int nb = wgid; nb < KB_TOTAL; nb += 8192){
    short8 af;
    #pragma unroll
    for (int j = 0; j < 8; ++j) af[j] = 0;
    if (half < 2)
      af = *(const short8*)(aggG + ((size_t)nb * 16 + row16) * 16 + half * 8);

    f32x4 acc[4];
    #pragma unroll
    for (int t = 0; t < 4; ++t){
      f32x4 a = {0.f, 0.f, 0.f, 0.f};
      acc[t] = __builtin_amdgcn_mfma_f32_16x16x32_bf16(af, bf[t], a, 0, 0, 0);
    }
    unsigned short* hp = h + (size_t)nb * 16 * 64;
    #pragma unroll
    for (int t = 0; t < 4; ++t){
      #pragma unroll
      for (int r = 0; r < 4; ++r){
        float v = acc[t][r] + bias[t];
        float e = v > 0.0f ? v : __expf(v) - 1.0f;
        hp[(half * 4 + r) * 64 + t * 16 + row16] = f2bf(e);
      }
    }
  }
}

// ------------- query = mean over nodes at s=S-1; qp = query @ Wq^T -------------
__global__ void k_query(const unsigned short* __restrict__ h,
                        const float* __restrict__ Wq, float* __restrict__ qp){
  __shared__ float part[256];
  __shared__ float q[64];
  int b = blockIdx.x, tid = threadIdx.x;
  int i = tid & 63, chunk = tid >> 6;
  const unsigned short* hb = h + ((size_t)(b * S + (S - 1)) * NN) * HH;
  float p = 0.0f;
  for (int n = chunk * 500; n < chunk * 500 + 500; ++n) p += bf2f(hb[n * HH + i]);
  part[tid] = p;
  __syncthreads();
  if (tid < 64) q[tid] = (part[tid] + part[tid+64] + part[tid+128] + part[tid+192]) * (1.0f / NN);
  __syncthreads();
  if (tid < 64){
    float acc = 0.0f;
    for (int k = 0; k < 64; ++k) acc += q[k] * Wq[tid * 64 + k];
    qp[b * 64 + tid] = acc;
  }
}

// ------------- scores: kp = keys @ Wk^T via MFMA; score = v . tanh(qp + kp) -------------
// wave owns 6 CONTIGUOUS key-blocks (never crosses a batch: 12000 = 6*2000)
__global__ __launch_bounds__(256) void k_scores(const unsigned short* __restrict__ h,
    const float* __restrict__ Wk, const float* __restrict__ vw,
    const float* __restrict__ qp, float* __restrict__ scores){
  int lane = threadIdx.x & 63;
  int wid = threadIdx.x >> 6;
  int wgid = blockIdx.x * 4 + wid;          // 0..7999
  int row16 = lane & 15, half = lane >> 4;

  short8 bf[4][2];
  #pragma unroll
  for (int t = 0; t < 4; ++t){
    int n = 16 * t + row16;
    #pragma unroll
    for (int s2 = 0; s2 < 2; ++s2){
      const float* wr = Wk + n * 64 + 32 * s2 + half * 8;
      short8 v;
      #pragma unroll
      for (int j = 0; j < 8; ++j) v[j] = (short)f2bf(wr[j]);
      bf[t][s2] = v;
    }
  }
  float vwv[4];
  #pragma unroll
  for (int t = 0; t < 4; ++t) vwv[t] = vw[16 * t + row16];

  int b = wgid / 2000;                       // batch is loop-invariant
  float qv[4];
  #pragma unroll
  for (int t = 0; t < 4; ++t) qv[t] = qp[b * 64 + 16 * t + row16];

  int kb0 = wgid * 6;
  #pragma unroll 2
  for (int i = 0; i < 6; ++i){
    int kb = kb0 + i;
    const short* hp = (const short*)h + (size_t)kb * 16 * 64;
    short8 af[2];
    #pragma unroll
    for (int s2 = 0; s2 < 2; ++s2)
      af[s2] = *(const short8*)(hp + row16 * 64 + 32 * s2 + half * 8);

    f32x4 acc[4];
    #pragma unroll
    for (int t = 0; t < 4; ++t){
      f32x4 a = {0.f, 0.f, 0.f, 0.f};
      a = __builtin_amdgcn_mfma_f32_16x16x32_bf16(af[0], bf[t][0], a, 0, 0, 0);
      a = __builtin_amdgcn_mfma_f32_16x16x32_bf16(af[1], bf[t][1], a, 0, 0, 0);
      acc[t] = a;
    }
    float part[4] = {0, 0, 0, 0};
    #pragma unroll
    for (int t = 0; t < 4; ++t){
      #pragma unroll
      for (int r = 0; r < 4; ++r)
        part[r] += vwv[t] * fast_tanh(qv[t] + acc[t][r]);
    }
    #pragma unroll
    for (int r = 0; r < 4; ++r){
      part[r] += __shfl_xor(part[r], 1);
      part[r] += __shfl_xor(part[r], 2);
      part[r] += __shfl_xor(part[r], 4);
      part[r] += __shfl_xor(part[r], 8);
    }
    if (row16 == 0){
      #pragma unroll
      for (int r = 0; r < 4; ++r) scores[kb * 16 + half * 4 + r] = part[r];
    }
  }
}

// ------------- softmax reductions over SN per batch -------------
__global__ void k_smax1(const float* __restrict__ scores, float* __restrict__ part2){
  __shared__ float red[256];
  int b = blockIdx.x >> 7, blk = blockIdx.x & 127, tid = threadIdx.x;
  const float* sc = scores + (size_t)b * SN + blk * 1500;
  float m = -1e30f;
  for (int k = tid; k < 1500; k += 256) m = fmaxf(m, sc[k]);
  red[tid] = m; __syncthreads();
  for (int s2 = 128; s2 > 0; s2 >>= 1){
    if (tid < s2) red[tid] = fmaxf(red[tid], red[tid + s2]);
    __syncthreads();
  }
  float bm = red[0]; __syncthreads();
  float sum = 0.f;
  for (int k = tid; k < 1500; k += 256) sum += __expf(sc[k] - bm);
  red[tid] = sum; __syncthreads();
  for (int s2 = 128; s2 > 0; s2 >>= 1){
    if (tid < s2) red[tid] += red[tid + s2];
    __syncthreads();
  }
  if (tid == 0){
    part2[(b * 128 + blk) * 2]     = bm;
    part2[(b * 128 + blk) * 2 + 1] = red[0];
  }
}

__global__ void k_smax2(const float* __restrict__ part2, float* __restrict__ Msum){
  int b = threadIdx.x;
  if (b < B){
    float M = -1e30f;
    for (int i = 0; i < 128; ++i) M = fmaxf(M, part2[(b * 128 + i) * 2]);
    float Ssum = 0.f;
    for (int i = 0; i < 128; ++i)
      Ssum += part2[(b * 128 + i) * 2 + 1] * __expf(part2[(b * 128 + i) * 2] - M);
    Msum[b] = M;
    Msum[4 + b] = 1.0f / Ssum;
  }
}

// ------------- fused: attn write + ctx_raw[b] = attn @ keys -------------
__global__ __launch_bounds__(256) void k_ctx(const float* __restrict__ scores,
    const float* __restrict__ Msum, const unsigned short* __restrict__ h,
    float* __restrict__ ctx_raw, float* __restrict__ outp){
  __shared__ float red[4 * 64];
  int lane = threadIdx.x & 63, wid = threadIdx.x >> 6;
  int b = blockIdx.x >> 7;                   // 4 x 128 blocks
  int blk = blockIdx.x & 127;
  int kr = lane >> 3, fb = lane & 7;
  float M = Msum[b], Si = Msum[4 + b];
  const float* sc = scores + (size_t)b * SN;
  const unsigned short* hb = h + (size_t)b * SN * 64;
  float* ao = outp + OUT_PRED + (size_t)b * SN;

  float acc[8];
  #pragma unroll
  for (int j = 0; j < 8; ++j) acc[j] = 0.0f;

  for (int k0 = (blk * 4 + wid) * 8; k0 < SN; k0 += 4096){
    int k = k0 + kr;
    float a = __expf(sc[k] - M) * Si;
    uint4 u = *(const uint4*)(hb + (size_t)k * 64 + fb * 8);
    if (fb == 0) ao[k] = a;
    acc[0] += a * __uint_as_float(u.x << 16);
    acc[1] += a * __uint_as_float(u.x & 0xffff0000u);
    acc[2] += a * __uint_as_float(u.y << 16);
    acc[3] += a * __uint_as_float(u.y & 0xffff0000u);
    acc[4] += a * __uint_as_float(u.z << 16);
    acc[5] += a * __uint_as_float(u.z & 0xffff0000u);
    acc[6] += a * __uint_as_float(u.w << 16);
    acc[7] += a * __uint_as_float(u.w & 0xffff0000u);
  }
  #pragma unroll
  for (int j = 0; j < 8; ++j){
    acc[j] += __shfl_xor(acc[j], 8);
    acc[j] += __shfl_xor(acc[j], 16);
    acc[j] += __shfl_xor(acc[j], 32);
  }
  if (kr == 0){
    #pragma unroll
    for (int j = 0; j < 8; ++j) red[wid * 64 + fb * 8 + j] = acc[j];
  }
  __syncthreads();
  if (wid == 0){
    float t = red[lane] + red[64 + lane] + red[128 + lane] + red[192 + lane];
    atomicAdd(&ctx_raw[b * 64 + lane], t);
  }
}

// ------------- Wv, LN1, GRU x2, LN2, pre1 (tiny, 1 block/batch, 128 thr) -------------
__global__ void k_head(const float* __restrict__ ctx_raw, const float* __restrict__ Wv,
    const float* __restrict__ ln1g, const float* __restrict__ ln1b,
    const float* __restrict__ Wih, const float* __restrict__ bih,
    const float* __restrict__ bhh,
    const float* __restrict__ ln2g, const float* __restrict__ ln2b,
    const float* __restrict__ pre1W, const float* __restrict__ pre1b,
    float* __restrict__ fout){
  __shared__ float cr[64], vec[64], stat[2];
  int b = blockIdx.x, t = threadIdx.x;
  if (t < 64) cr[t] = ctx_raw[b * 64 + t];
  __syncthreads();
  float c = 0.f;
  if (t < 64){
    for (int i = 0; i < 64; ++i) c += cr[i] * Wv[t * 64 + i];
  }
  __syncthreads();
  if (t < 64) vec[t] = c;
  __syncthreads();
  if (t == 0){
    float mu = 0; for (int i = 0; i < 64; ++i) mu += vec[i]; mu *= (1.f/64.f);
    float va = 0; for (int i = 0; i < 64; ++i){ float d = vec[i] - mu; va += d * d; }
    va *= (1.f/64.f);
    stat[0] = mu; stat[1] = rsqrtf(va + 1e-5f);
  }
  __syncthreads();
  if (t < 64) cr[t] = (vec[t] - stat[0]) * stat[1] * ln1g[t] + ln1b[t];
  __syncthreads();
  for (int l = 0; l < 2; ++l){
    float nv = 0.f;
    if (t < 64){
      const float* W = Wih + l * 192 * 64;
      const float* bi = bih + l * 192;
      const float* bh = bhh + l * 192;
      float ir = bi[t], iz = bi[64 + t], in_ = bi[128 + t];
      for (int i = 0; i < 64; ++i){
        float v = cr[i];
        ir  += v * W[t * 64 + i];
        iz  += v * W[(64 + t) * 64 + i];
        in_ += v * W[(128 + t) * 64 + i];
      }
      float r = sigm(ir + bh[t]);
      float z = sigm(iz + bh[64 + t]);
      float nn2 = fast_tanh(in_ + r * bh[128 + t]);
      nv = (1.0f - z) * nn2;
    }
    __syncthreads();
    if (t < 64) cr[t] = nv;
    __syncthreads();
  }
  if (t == 0){
    float mu = 0; for (int i = 0; i < 64; ++i) mu += cr[i]; mu *= (1.f/64.f);
    float va = 0; for (int i = 0; i < 64; ++i){ float d = cr[i] - mu; va += d * d; }
    va *= (1.f/64.f);
    stat[0] = mu; stat[1] = rsqrtf(va + 1e-5f);
  }
  __syncthreads();
  if (t < 64) vec[t] = (cr[t] - stat[0]) * stat[1] * ln2g[t] + ln2b[t];
  __syncthreads();
  float fc = pre1b[t];
  for (int j = 0; j < 64; ++j) fc += vec[j] * pre1W[t * 64 + j];
  fout[b * 128 + t] = eluf(fc);
}

// ------------- pre2 projection (MFMA) + monotonic quantile head -------------
__global__ __launch_bounds__(256) void k_out(const float* __restrict__ f_g,
    const float* __restrict__ pre2W, const float* __restrict__ pre2b,
    const float* __restrict__ lowW, const float* __restrict__ lowb,
    const float* __restrict__ incW, const float* __restrict__ incb,
    float* __restrict__ outp){
  __shared__ float w72T[64 * 72];          // head weights transposed [j][out], 18.4 KB
  __shared__ float nf_lds[4][64 * 4];      // per-wave nf[j][b], 4 KB
  int tid = threadIdx.x;
  int lane = tid & 63, wid = tid >> 6;
  int row16 = lane & 15, half = lane >> 4;

  for (int i = tid; i < 64 * 72; i += 256){
    int j = i / 72, o = i - j * 72;
    w72T[i] = (o < 24) ? lowW[o * 64 + j] : incW[(o - 24) * 64 + j];
  }

  short8 bfr[4];
  #pragma unroll
  for (int s = 0; s < 4; ++s){
    short8 v;
    #pragma unroll
    for (int j = 0; j < 8; ++j) v[j] = 0;
    if (row16 < 4){
      const float* fr = f_g + row16 * 128 + s * 32 + half * 8;
      #pragma unroll
      for (int j = 0; j < 8; ++j) v[j] = (short)f2bf(fr[j]);
    }
    bfr[s] = v;
  }
  __syncthreads();

  int n = blockIdx.x * 4 + wid;            // exactly 2000 nodes
  float* nfw = &nf_lds[wid][0];
  #pragma unroll
  for (int rb = 0; rb < 4; ++rb){
    f32x4 acc = {0.f, 0.f, 0.f, 0.f};
    #pragma unroll
    for (int s = 0; s < 4; ++s){
      const float* ar = pre2W + ((size_t)(n * 64 + rb * 16 + row16)) * 128 + s * 32 + half * 8;
      short8 av;
      #pragma unroll
      for (int j = 0; j < 8; ++j) av[j] = (short)f2bf(ar[j]);
      acc = __builtin_amdgcn_mfma_f32_16x16x32_bf16(av, bfr[s], acc, 0, 0, 0);
    }
    if (row16 < 4){
      #pragma unroll
      for (int r = 0; r < 4; ++r){
        int j = rb * 16 + half * 4 + r;
        nfw[j * 4 + row16] = acc[r] + pre2b[n * 64 + j];
      }
    }
  }
  __syncthreads();

  #pragma unroll
  for (int rnd = 0; rnd < 2; ++rnd){
    int wo = rnd * 16 + (lane >> 2);
    int b = lane & 3;
    if (wo < 24){
      float q0 = lowb[wo], i0 = incb[2 * wo], i1 = incb[2 * wo + 1];
      #pragma unroll 4
      for (int j = 0; j < 64; ++j){
        float v = nfw[j * 4 + b];
        q0 += v * w72T[j * 72 + wo];
        i0 += v * w72T[j * 72 + 24 + 2 * wo];
        i1 += v * w72T[j * 72 + 24 + 2 * wo + 1];
      }
      float p0 = q0;
      float p1 = p0 + softplusf_(i0);
      float p2 = p1 + softplusf_(i1);
      size_t ob = ((size_t)(b * 24 + wo) * NN + n) * 3;
      outp[ob] = p0; outp[ob + 1] = p1; outp[ob + 2] = p2;
    }
  }
}

extern "C" void kernel_launch(void* const* d_in, const int* in_sizes, int n_in,
                              void* d_out, int out_size, void* d_ws, size_t ws_size,
                              hipStream_t stream){
  const float* x     = (const float*)d_in[0];
  const int*   ei    = (const int*)d_in[1];
  const float* ew    = (const float*)d_in[2];
  const float* Wg    = (const float*)d_in[3];
  const float* bg    = (const float*)d_in[4];
  const float* Wq    = (const float*)d_in[5];
  const float* Wk    = (const float*)d_in[6];
  const float* Wv    = (const float*)d_in[7];
  const float* vw    = (const float*)d_in[8];
  const float* ln1g  = (const float*)d_in[10];
  const float* ln1b  = (const float*)d_in[11];
  const float* Wih   = (const float*)d_in[12];
  const float* bih   = (const float*)d_in[14];
  const float* bhh   = (const float*)d_in[15];
  const float* ln2g  = (const float*)d_in[16];
  const float* ln2b  = (const float*)d_in[17];
  const float* pre1W = (const float*)d_in[18];
  const float* pre1b = (const float*)d_in[19];
  const float* pre2W = (const float*)d_in[20];
  const float* pre2b = (const float*)d_in[21];
  const float* lowW  = (const float*)d_in[22];
  const float* lowb  = (const float*)d_in[23];
  const float* incW  = (const float*)d_in[24];
  const float* incb  = (const float*)d_in[25];
  float* outp = (float*)d_out;

  char* ws = (char*)d_ws;
  size_t off = 0;
  auto alloc = [&](size_t bytes) -> char* {
    char* p = ws + off;
    off += (bytes + 255) & ~(size_t)255;
    return p;
  };
  unsigned short* h  = (unsigned short*)alloc((size_t)BSN * 64 * 2); // 98.3 MB bf16
  unsigned* aggG     = (unsigned*)alloc((size_t)BSN * 8 * 4);        // 24.6 MB bf16-packed
  float* scores      = (float*)alloc((size_t)BSN * 4);
  int*   rowptr      = (int*)alloc((NN + 1) * 4);
  uint2* epack       = (uint2*)alloc((EE + NN) * 8);
  float* degw        = (float*)alloc(NN * 4);
  int*   cnt         = (int*)alloc(NN * 4);
  int*   curs        = (int*)alloc(NN * 4);
  float* qp          = (float*)alloc(B * 64 * 4);
  float* part2       = (float*)alloc(B * 128 * 2 * 4);
  float* Msum        = (float*)alloc(8 * 4);
  float* ctx_raw     = (float*)alloc(B * 64 * 4);
  float* f_g         = (float*)alloc(B * 128 * 4);
  (void)ws_size; (void)in_sizes; (void)n_in; (void)out_size;

  (void)hipMemsetAsync(ctx_raw, 0, B * 64 * 4, stream);
  k_pinit <<<(NN + 255) / 256, 256, 0, stream>>>(degw, cnt);
  k_deg   <<<(EE + 255) / 256, 256, 0, stream>>>(ei, ew, degw, cnt);
  k_scan  <<<1, 256, 0, stream>>>(cnt, degw, rowptr, curs);
  k_fill  <<<(EE + 255) / 256, 256, 0, stream>>>(ei, ew, degw, curs, epack);
  k_agg   <<<SLICES, 512, 0, stream>>>(x, rowptr, epack, aggG);
  k_xform <<<2048, 256, 0, stream>>>((const unsigned short*)aggG, Wg, bg, h);
  k_query <<<B, 256, 0, stream>>>(h, Wq, qp);
  k_scores<<<2000, 256, 0, stream>>>(h, Wk, vw, qp, scores);
  k_smax1 <<<512, 256, 0, stream>>>(scores, part2);
  k_smax2 <<<1, 64, 0, stream>>>(part2, Msum);
  k_ctx   <<<512, 256, 0, stream>>>(scores, Msum, h, ctx_raw, outp);
  k_head  <<<B, 128, 0, stream>>>(ctx_raw, Wv, ln1g, ln1b, Wih, bih, bhh,
                                  ln2g, ln2b, pre1W, pre1b, f_g);
  k_out   <<<500, 256, 0, stream>>>(f_g, pre2W, pre2b, lowW, lowb, incW, incb, outp);
}